// Round 3
// baseline (65.643 us; speedup 1.0000x reference)
//
#include <hip/hip_runtime.h>

typedef unsigned short u16;
typedef __bf16 bf16;
typedef __bf16 bf16x8 __attribute__((ext_vector_type(8)));
typedef float f32x4 __attribute__((ext_vector_type(4)));

// Problem constants: B=4, S=2048, DIM=1024, DK=DV=128, rows = B*S = 8192.

__device__ __forceinline__ void gl_lds16(const void* g, void* l) {
  __builtin_amdgcn_global_load_lds(
      (const __attribute__((address_space(1))) void*)g,
      (__attribute__((address_space(3))) void*)l, 16, 0, 0);
}

__device__ __forceinline__ u16 bfbits(float f) {
  return __builtin_bit_cast(u16, (bf16)f);
}

// ---------------- W transpose + convert: Wt[m][n][k] = bf16(W_m[k][n]) -------
// LDS-transpose tile 64k x 64n: coalesced loads AND coalesced ushort4 stores.
// grid: 3 m * 16 ktiles * 2 ntiles = 96 blocks.
__global__ __launch_bounds__(256) void wprep_kernel(
    const float* __restrict__ Wq, const float* __restrict__ Wk,
    const float* __restrict__ Wv, u16* __restrict__ Wt) {
  __shared__ u16 st[64][68];
  const int tid = threadIdx.x;
  const int m = blockIdx.x >> 5, rem = blockIdx.x & 31, kt = rem >> 1, nt = rem & 1;
  const float* W = (m == 0) ? Wq : (m == 1) ? Wk : Wv;
  const int k0 = kt * 64, n0 = nt * 64;
#pragma unroll
  for (int i = 0; i < 4; ++i) {
    int kk = i * 16 + (tid >> 4), nn = (tid & 15) * 4;
    f32x4 w = *(const f32x4*)&W[(size_t)(k0 + kk) * 128 + n0 + nn];
    st[kk][nn]     = bfbits(w[0]); st[kk][nn + 1] = bfbits(w[1]);
    st[kk][nn + 2] = bfbits(w[2]); st[kk][nn + 3] = bfbits(w[3]);
  }
  __syncthreads();
#pragma unroll
  for (int i = 0; i < 4; ++i) {
    int nn = i * 16 + (tid >> 4), kk = (tid & 15) * 4;
    ushort4 u;
    u.x = st[kk][nn]; u.y = st[kk + 1][nn]; u.z = st[kk + 2][nn]; u.w = st[kk + 3][nn];
    *(ushort4*)&Wt[(size_t)m * 131072 + (size_t)(n0 + nn) * 1024 + k0 + kk] = u;
  }
}

// ---------------- QKV projection GEMM ---------------------------------------
// grid (128, 3); block 256 (4 waves, 2x2). Tile 64x128, BK=64.
// Double-buffered, 2-phase prefetch (T3-min). XOR chunk-swizzle, linear LDS
// dest for global_load_lds + pre-swizzled global source (rule #21).
__global__ __launch_bounds__(256) void qkv_gemm(
    const float* __restrict__ x, const u16* __restrict__ Wt,
    const float* __restrict__ bq, const float* __restrict__ bk, const float* __restrict__ bv,
    u16* __restrict__ qb, u16* __restrict__ kb, u16* __restrict__ vt)
{
  __shared__ __attribute__((aligned(16))) float sx[2][64 * 64];   // 2 x 16 KB
  __shared__ __attribute__((aligned(16))) u16   sw[2][128 * 64];  // 2 x 16 KB
  const int tid = threadIdx.x, wid = tid >> 6, lane = tid & 63;
  const int m = blockIdx.y;
  const int row0 = blockIdx.x * 64;
  const u16* W = Wt + (size_t)m * 131072;
  const int wr = wid >> 1, wc = wid & 1;

  auto STAGE = [&](int buf, int k0) {
#pragma unroll
    for (int i = 0; i < 4; ++i) {  // x-tile: 64 rows x 16 chunks of 16B
      int fc = i * 256 + tid; int r = fc >> 4, c = fc & 15;
      gl_lds16(x + (size_t)(row0 + r) * 1024 + k0 + ((c ^ (r & 15)) << 2),
               (char*)&sx[buf][0] + fc * 16);
    }
#pragma unroll
    for (int i = 0; i < 4; ++i) {  // W-tile: 128 rows x 8 chunks of 16B
      int fc = i * 256 + tid; int r = fc >> 3, c = fc & 7;
      gl_lds16(W + (size_t)r * 1024 + k0 + ((c ^ (r & 7)) << 3),
               (char*)&sw[buf][0] + fc * 16);
    }
  };

  f32x4 acc[2][4] = {};
  STAGE(0, 0);
  asm volatile("s_waitcnt vmcnt(0)" ::: "memory");
  __syncthreads();
  int cur = 0;

  for (int kt = 0; kt < 16; ++kt) {
    if (kt < 15) STAGE(cur ^ 1, (kt + 1) * 64);
    const float* sxc = &sx[cur][0];
    const u16*   swc = &sw[cur][0];
#pragma unroll
    for (int ks = 0; ks < 2; ++ks) {
      bf16x8 af[2], bfr[4];
#pragma unroll
      for (int mr = 0; mr < 2; ++mr) {
        int row = wr * 32 + mr * 16 + (lane & 15);
        int c0 = ks * 8 + (lane >> 4) * 2;
        f32x4 lo = *(const f32x4*)(sxc + row * 64 + ((c0 ^ (row & 15)) << 2));
        f32x4 hi = *(const f32x4*)(sxc + row * 64 + (((c0 + 1) ^ (row & 15)) << 2));
        bf16x8 v;
        v[0] = (bf16)lo[0]; v[1] = (bf16)lo[1]; v[2] = (bf16)lo[2]; v[3] = (bf16)lo[3];
        v[4] = (bf16)hi[0]; v[5] = (bf16)hi[1]; v[6] = (bf16)hi[2]; v[7] = (bf16)hi[3];
        af[mr] = v;
      }
#pragma unroll
      for (int nr = 0; nr < 4; ++nr) {
        int row = wc * 64 + nr * 16 + (lane & 15);
        int ch = (ks * 4 + (lane >> 4)) ^ (row & 7);
        bfr[nr] = *(const bf16x8*)(swc + row * 64 + ch * 8);
      }
#pragma unroll
      for (int mr = 0; mr < 2; ++mr)
#pragma unroll
        for (int nr = 0; nr < 4; ++nr)
          acc[mr][nr] = __builtin_amdgcn_mfma_f32_16x16x32_bf16(af[mr], bfr[nr], acc[mr][nr], 0, 0, 0);
    }
    if (kt < 15) {
      asm volatile("s_waitcnt vmcnt(0)" ::: "memory");
      __syncthreads();
      cur ^= 1;
    }
  }

  const float* bias = (m == 0) ? bq : (m == 1) ? bk : bv;
  u16* qk = (m == 0) ? qb : kb;
#pragma unroll
  for (int mr = 0; mr < 2; ++mr) {
#pragma unroll
    for (int nr = 0; nr < 4; ++nr) {
      int col = wc * 64 + nr * 16 + (lane & 15);
      float bc = bias[col];
      int grow = row0 + wr * 32 + mr * 16 + (lane >> 4) * 4;
      if (m == 2) {
        int b = grow >> 11, s = grow & 2047;
        ushort4 u;
        u.x = bfbits(acc[mr][nr][0] + bc);
        u.y = bfbits(acc[mr][nr][1] + bc);
        u.z = bfbits(acc[mr][nr][2] + bc);
        u.w = bfbits(acc[mr][nr][3] + bc);
        *(ushort4*)&vt[(size_t)b * 262144 + (size_t)col * 2048 + s] = u;
      } else {
#pragma unroll
        for (int r = 0; r < 4; ++r)
          qk[(size_t)(grow + r) * 128 + col] = bfbits(acc[mr][nr][r] + bc);
      }
    }
  }
}

// ---------------- Flash attention with 4-way KV split -----------------------
// grid (32 q-tiles, 4 splits, 4 batch); block 256 (4 waves x 16 q-rows).
// Double-buffered K/V tiles, 2-phase prefetch, XOR chunk-swizzle.
// LDS: 2*16 + 2*16 + 9 = 73 KB -> 2 blocks/CU.
__global__ __launch_bounds__(256) void attn_kernel(
    const u16* __restrict__ qb, const u16* __restrict__ kb, const u16* __restrict__ vt,
    float* __restrict__ Opart, float* __restrict__ Mws, float* __restrict__ Lws)
{
  __shared__ __attribute__((aligned(16))) u16 sk[2][64 * 128];
  __shared__ __attribute__((aligned(16))) u16 sv[2][128 * 64];
  __shared__ __attribute__((aligned(16))) u16 sp[64 * 72];
  const int tid = threadIdx.x, wid = tid >> 6, lane = tid & 63;
  const int qt = blockIdx.x, split = blockIdx.y, b = blockIdx.z;
  const size_t qg0 = (size_t)b * 2048 + qt * 64 + wid * 16;
  const u16* kbase = kb + ((size_t)b * 2048 + split * 512) * 128;
  const u16* vbase = vt + (size_t)b * 262144 + split * 512;

  auto STAGE = [&](int buf, int t) {
#pragma unroll
    for (int i = 0; i < 4; ++i) {  // K-tile: 64 rows x 16 chunks of 16B
      int fc = i * 256 + tid; int r = fc >> 4, c = fc & 15;
      gl_lds16(kbase + (size_t)(t * 64 + r) * 128 + ((c ^ (r & 7)) << 3),
               (char*)&sk[buf][0] + fc * 16);
    }
#pragma unroll
    for (int i = 0; i < 4; ++i) {  // V^T-tile: 128 rows x 8 chunks of 16B
      int fc = i * 256 + tid; int r = fc >> 3, c = fc & 7;
      gl_lds16(vbase + (size_t)r * 2048 + t * 64 + ((c ^ (r & 7)) << 3),
               (char*)&sv[buf][0] + fc * 16);
    }
  };

  STAGE(0, 0);
  bf16x8 qf[4];
#pragma unroll
  for (int kg = 0; kg < 4; ++kg)
    qf[kg] = *(const bf16x8*)&qb[(qg0 + (lane & 15)) * 128 + kg * 32 + (lane >> 4) * 8];

  float mrow[4] = {-INFINITY, -INFINITY, -INFINITY, -INFINITY};
  float lrow[4] = {0.f, 0.f, 0.f, 0.f};
  f32x4 acc_o[8] = {};
  const float scale = 0.08838834764831845f;   // 128^-0.5

  asm volatile("s_waitcnt vmcnt(0)" ::: "memory");
  __syncthreads();
  int cur = 0;

  for (int t = 0; t < 8; ++t) {
    if (t < 7) STAGE(cur ^ 1, t + 1);
    const u16* skc = &sk[cur][0];
    const u16* svc = &sv[cur][0];

    // S = Q K^T
    f32x4 s[4] = {};
#pragma unroll
    for (int kg = 0; kg < 4; ++kg)
#pragma unroll
      for (int jg = 0; jg < 4; ++jg) {
        int row = jg * 16 + (lane & 15);
        int ch = (kg * 4 + (lane >> 4)) ^ (row & 7);
        bf16x8 kf = *(const bf16x8*)(skc + row * 128 + ch * 8);
        s[jg] = __builtin_amdgcn_mfma_f32_16x16x32_bf16(qf[kg], kf, s[jg], 0, 0, 0);
      }

    // online softmax per q-row (row-reduce across the 16 j-lanes)
    float al[4]; float pr[4][4];
#pragma unroll
    for (int r = 0; r < 4; ++r) {
      float s0 = s[0][r] * scale, s1 = s[1][r] * scale, s2 = s[2][r] * scale, s3 = s[3][r] * scale;
      float tm = fmaxf(fmaxf(s0, s1), fmaxf(s2, s3));
      tm = fmaxf(tm, __shfl_xor(tm, 1));
      tm = fmaxf(tm, __shfl_xor(tm, 2));
      tm = fmaxf(tm, __shfl_xor(tm, 4));
      tm = fmaxf(tm, __shfl_xor(tm, 8));
      float mn = fmaxf(mrow[r], tm);
      float p0 = __expf(s0 - mn), p1 = __expf(s1 - mn), p2 = __expf(s2 - mn), p3 = __expf(s3 - mn);
      pr[0][r] = p0; pr[1][r] = p1; pr[2][r] = p2; pr[3][r] = p3;
      float rs = p0 + p1 + p2 + p3;
      rs += __shfl_xor(rs, 1);
      rs += __shfl_xor(rs, 2);
      rs += __shfl_xor(rs, 4);
      rs += __shfl_xor(rs, 8);
      float a = __expf(mrow[r] - mn);
      lrow[r] = lrow[r] * a + rs;
      mrow[r] = mn;
      al[r] = a;
    }
#pragma unroll
    for (int dg = 0; dg < 8; ++dg) {
      acc_o[dg][0] *= al[0]; acc_o[dg][1] *= al[1];
      acc_o[dg][2] *= al[2]; acc_o[dg][3] *= al[3];
    }

    // P: C-layout -> A-layout via wave-private LDS roundtrip
#pragma unroll
    for (int jg = 0; jg < 4; ++jg)
#pragma unroll
      for (int r = 0; r < 4; ++r)
        sp[(wid * 16 + (lane >> 4) * 4 + r) * 72 + jg * 16 + (lane & 15)] = bfbits(pr[jg][r]);
    asm volatile("s_waitcnt lgkmcnt(0)" ::: "memory");
    bf16x8 pf[2];
#pragma unroll
    for (int k2 = 0; k2 < 2; ++k2)
      pf[k2] = *(const bf16x8*)&sp[(wid * 16 + (lane & 15)) * 72 + k2 * 32 + (lane >> 4) * 8];

    // O += P V
#pragma unroll
    for (int dg = 0; dg < 8; ++dg)
#pragma unroll
      for (int k2 = 0; k2 < 2; ++k2) {
        int row = dg * 16 + (lane & 15);
        int ch = (k2 * 4 + (lane >> 4)) ^ (row & 7);
        bf16x8 vf = *(const bf16x8*)(svc + row * 64 + ch * 8);
        acc_o[dg] = __builtin_amdgcn_mfma_f32_16x16x32_bf16(pf[k2], vf, acc_o[dg], 0, 0, 0);
      }
    if (t < 7) {
      asm volatile("s_waitcnt vmcnt(0)" ::: "memory");
      __syncthreads();
      cur ^= 1;
    }
  }

  const size_t prow = (size_t)split * 8192 + qg0;
#pragma unroll
  for (int dg = 0; dg < 8; ++dg)
#pragma unroll
    for (int r = 0; r < 4; ++r)
      Opart[(prow + (lane >> 4) * 4 + r) * 128 + dg * 16 + (lane & 15)] = acc_o[dg][r];
  if ((lane & 15) == 0) {
#pragma unroll
    for (int r = 0; r < 4; ++r) {
      Mws[prow + (lane >> 4) * 4 + r] = mrow[r];
      Lws[prow + (lane >> 4) * 4 + r] = lrow[r];
    }
  }
}

// ---------------- combine the 4 KV-split partials (f32x4 vectorized) --------
__global__ __launch_bounds__(256) void combine_kernel(
    const float* __restrict__ Opart, const float* __restrict__ Mws,
    const float* __restrict__ Lws, float* __restrict__ out)
{
  int idx4 = blockIdx.x * 256 + threadIdx.x;   // 0..262143 (f32x4 units)
  int row = idx4 >> 5;                          // 32 vec4 per 128-col row
  float m0 = Mws[row], m1 = Mws[8192 + row], m2 = Mws[16384 + row], m3 = Mws[24576 + row];
  float ms = fmaxf(fmaxf(m0, m1), fmaxf(m2, m3));
  float w0 = __expf(m0 - ms), w1 = __expf(m1 - ms), w2 = __expf(m2 - ms), w3 = __expf(m3 - ms);
  float den = w0 * Lws[row] + w1 * Lws[8192 + row] + w2 * Lws[16384 + row] + w3 * Lws[24576 + row];
  float inv = 1.0f / den;
  f32x4 o0 = *(const f32x4*)&Opart[(size_t)idx4 * 4];
  f32x4 o1 = *(const f32x4*)&Opart[1048576 + (size_t)idx4 * 4];
  f32x4 o2 = *(const f32x4*)&Opart[2097152 + (size_t)idx4 * 4];
  f32x4 o3 = *(const f32x4*)&Opart[3145728 + (size_t)idx4 * 4];
  f32x4 r = (o0 * w0 + o1 * w1 + o2 * w2 + o3 * w3) * inv;
  *(f32x4*)&out[(size_t)idx4 * 4] = r;
}

// ---------------- launch ----------------------------------------------------
// Workspace layout (~23.3 MB):
//   0      : qb   (8192x128 bf16, 2 MB)
//   2 MB   : kb   (2 MB)
//   4 MB   : vt   ([4][128][2048] bf16, 2 MB)
//   6 MB   : Wt   (3x[128][1024] bf16, 0.75 MB)
//   7 MB   : Opart ([4][8192][128] f32, 16 MB)
//   23 MB  : Mws  ([4][8192] f32, 128 KB)
//   23 MB+128 KB : Lws (128 KB)
extern "C" void kernel_launch(void* const* d_in, const int* in_sizes, int n_in,
                              void* d_out, int out_size, void* d_ws, size_t ws_size,
                              hipStream_t stream)
{
  (void)in_sizes; (void)n_in; (void)out_size; (void)ws_size;
  const float* x  = (const float*)d_in[0];
  const float* Wq = (const float*)d_in[1];
  const float* bq = (const float*)d_in[2];
  const float* Wk = (const float*)d_in[3];
  const float* bk = (const float*)d_in[4];
  const float* Wv = (const float*)d_in[5];
  const float* bv = (const float*)d_in[6];
  char* ws = (char*)d_ws;
  u16* qbuf   = (u16*)(ws);
  u16* kbuf   = (u16*)(ws + (2u << 20));
  u16* vtbuf  = (u16*)(ws + (4u << 20));
  u16* Wt     = (u16*)(ws + (6u << 20));
  float* Opart = (float*)(ws + (7u << 20));
  float* Mws   = (float*)(ws + (23u << 20));
  float* Lws   = (float*)(ws + (23u << 20) + (128u << 10));

  wprep_kernel<<<96, 256, 0, stream>>>(Wq, Wk, Wv, Wt);
  qkv_gemm<<<dim3(128, 3), 256, 0, stream>>>(x, Wt, bq, bk, bv, qbuf, kbuf, vtbuf);
  attn_kernel<<<dim3(32, 4, 4), 256, 0, stream>>>(qbuf, kbuf, vtbuf, Opart, Mws, Lws);
  combine_kernel<<<1024, 256, 0, stream>>>(Opart, Mws, Lws, (float*)d_out);
}

// Round 5
// 63.686 us; speedup vs baseline: 1.0307x; 1.0307x over previous
//
#include <hip/hip_runtime.h>

typedef unsigned short u16;
typedef unsigned int u32;
typedef __bf16 bf16;
typedef __bf16 bf16x8 __attribute__((ext_vector_type(8)));
typedef float f32x4 __attribute__((ext_vector_type(4)));
typedef u32 u32x2 __attribute__((ext_vector_type(2)));
typedef u32 u32x4 __attribute__((ext_vector_type(4)));

// Problem constants: B=4, S=2048, DIM=1024, DK=DV=128, rows = B*S = 8192.

__device__ __forceinline__ void gl_lds16(const void* g, void* l) {
  __builtin_amdgcn_global_load_lds(
      (const __attribute__((address_space(1))) void*)g,
      (__attribute__((address_space(3))) void*)l, 16, 0, 0);
}

__device__ __forceinline__ u16 bfbits(float f) {
  return __builtin_bit_cast(u16, (bf16)f);
}
__device__ __forceinline__ u32 pk2(float lo, float hi) {
  return (u32)bfbits(lo) | ((u32)bfbits(hi) << 16);
}

// ---------------- W transpose + convert: Wt[m][n][k] = bf16(W_m[k][n]) -------
__global__ __launch_bounds__(256) void wprep_kernel(
    const float* __restrict__ Wq, const float* __restrict__ Wk,
    const float* __restrict__ Wv, u16* __restrict__ Wt) {
  __shared__ u16 st[64][68];
  const int tid = threadIdx.x;
  const int m = blockIdx.x >> 5, rem = blockIdx.x & 31, kt = rem >> 1, nt = rem & 1;
  const float* W = (m == 0) ? Wq : (m == 1) ? Wk : Wv;
  const int k0 = kt * 64, n0 = nt * 64;
#pragma unroll
  for (int i = 0; i < 4; ++i) {
    int kk = i * 16 + (tid >> 4), nn = (tid & 15) * 4;
    f32x4 w = *(const f32x4*)&W[(size_t)(k0 + kk) * 128 + n0 + nn];
    st[kk][nn]     = bfbits(w[0]); st[kk][nn + 1] = bfbits(w[1]);
    st[kk][nn + 2] = bfbits(w[2]); st[kk][nn + 3] = bfbits(w[3]);
  }
  __syncthreads();
#pragma unroll
  for (int i = 0; i < 4; ++i) {
    int nn = i * 16 + (tid >> 4), kk = (tid & 15) * 4;
    ushort4 u;
    u.x = st[kk][nn]; u.y = st[kk + 1][nn]; u.z = st[kk + 2][nn]; u.w = st[kk + 3][nn];
    *(ushort4*)&Wt[(size_t)m * 131072 + (size_t)(n0 + nn) * 1024 + k0 + kk] = u;
  }
}

// ---------------- QKV projection GEMM (unchanged from R3) --------------------
__global__ __launch_bounds__(256) void qkv_gemm(
    const float* __restrict__ x, const u16* __restrict__ Wt,
    const float* __restrict__ bq, const float* __restrict__ bk, const float* __restrict__ bv,
    u16* __restrict__ qb, u16* __restrict__ kb, u16* __restrict__ vt)
{
  __shared__ __attribute__((aligned(16))) float sx[2][64 * 64];
  __shared__ __attribute__((aligned(16))) u16   sw[2][128 * 64];
  const int tid = threadIdx.x, wid = tid >> 6, lane = tid & 63;
  const int m = blockIdx.y;
  const int row0 = blockIdx.x * 64;
  const u16* W = Wt + (size_t)m * 131072;
  const int wr = wid >> 1, wc = wid & 1;

  auto STAGE = [&](int buf, int k0) {
#pragma unroll
    for (int i = 0; i < 4; ++i) {
      int fc = i * 256 + tid; int r = fc >> 4, c = fc & 15;
      gl_lds16(x + (size_t)(row0 + r) * 1024 + k0 + ((c ^ (r & 15)) << 2),
               (char*)&sx[buf][0] + fc * 16);
    }
#pragma unroll
    for (int i = 0; i < 4; ++i) {
      int fc = i * 256 + tid; int r = fc >> 3, c = fc & 7;
      gl_lds16(W + (size_t)r * 1024 + k0 + ((c ^ (r & 7)) << 3),
               (char*)&sw[buf][0] + fc * 16);
    }
  };

  f32x4 acc[2][4] = {};
  STAGE(0, 0);
  asm volatile("s_waitcnt vmcnt(0)" ::: "memory");
  __syncthreads();
  int cur = 0;

  for (int kt = 0; kt < 16; ++kt) {
    if (kt < 15) STAGE(cur ^ 1, (kt + 1) * 64);
    const float* sxc = &sx[cur][0];
    const u16*   swc = &sw[cur][0];
#pragma unroll
    for (int ks = 0; ks < 2; ++ks) {
      bf16x8 af[2], bfr[4];
#pragma unroll
      for (int mr = 0; mr < 2; ++mr) {
        int row = wr * 32 + mr * 16 + (lane & 15);
        int c0 = ks * 8 + (lane >> 4) * 2;
        f32x4 lo = *(const f32x4*)(sxc + row * 64 + ((c0 ^ (row & 15)) << 2));
        f32x4 hi = *(const f32x4*)(sxc + row * 64 + (((c0 + 1) ^ (row & 15)) << 2));
        bf16x8 v;
        v[0] = (bf16)lo[0]; v[1] = (bf16)lo[1]; v[2] = (bf16)lo[2]; v[3] = (bf16)lo[3];
        v[4] = (bf16)hi[0]; v[5] = (bf16)hi[1]; v[6] = (bf16)hi[2]; v[7] = (bf16)hi[3];
        af[mr] = v;
      }
#pragma unroll
      for (int nr = 0; nr < 4; ++nr) {
        int row = wc * 64 + nr * 16 + (lane & 15);
        int ch = (ks * 4 + (lane >> 4)) ^ (row & 7);
        bfr[nr] = *(const bf16x8*)(swc + row * 64 + ch * 8);
      }
#pragma unroll
      for (int mr = 0; mr < 2; ++mr)
#pragma unroll
        for (int nr = 0; nr < 4; ++nr)
          acc[mr][nr] = __builtin_amdgcn_mfma_f32_16x16x32_bf16(af[mr], bfr[nr], acc[mr][nr], 0, 0, 0);
    }
    if (kt < 15) {
      asm volatile("s_waitcnt vmcnt(0)" ::: "memory");
      __syncthreads();
      cur ^= 1;
    }
  }

  const float* bias = (m == 0) ? bq : (m == 1) ? bk : bv;
  u16* qk = (m == 0) ? qb : kb;
#pragma unroll
  for (int mr = 0; mr < 2; ++mr) {
#pragma unroll
    for (int nr = 0; nr < 4; ++nr) {
      int col = wc * 64 + nr * 16 + (lane & 15);
      float bc = bias[col];
      int grow = row0 + wr * 32 + mr * 16 + (lane >> 4) * 4;
      if (m == 2) {
        int b = grow >> 11, s = grow & 2047;
        ushort4 u;
        u.x = bfbits(acc[mr][nr][0] + bc);
        u.y = bfbits(acc[mr][nr][1] + bc);
        u.z = bfbits(acc[mr][nr][2] + bc);
        u.w = bfbits(acc[mr][nr][3] + bc);
        *(ushort4*)&vt[(size_t)b * 262144 + (size_t)col * 2048 + s] = u;
      } else {
#pragma unroll
        for (int r = 0; r < 4; ++r)
          qk[(size_t)(grow + r) * 128 + col] = bfbits(acc[mr][nr][r] + bc);
      }
    }
  }
}

// ---------------- Flash attention, swapped-operand, zero-shuffle P -----------
// S^T = mfma(A=K, B=Q): lane owns q = lane&15, j = jg*16 + g*4 + r.
// Softmax lane-local (16 values) + 2 shfl_xor.
// PV: k-slot mapping sigma_{k2}(g*8+e) = (2k2+(e>>2))*16 + g*4 + (e&3) makes
// the P B-fragment exactly the lane's own Wp words (NO shuffles); the V^T
// A-fragment becomes two b64 LDS reads per MFMA.
// O = mfma(A=V^T, B=P): lane owns q = lane&15, d = dg*16 + g*4 + r.
__global__ __launch_bounds__(256) void attn_kernel(
    const u16* __restrict__ qb, const u16* __restrict__ kb, const u16* __restrict__ vt,
    float* __restrict__ Opart, float* __restrict__ Mws, float* __restrict__ Lws)
{
  __shared__ __attribute__((aligned(16))) u16 sk[2][64 * 128];
  __shared__ __attribute__((aligned(16))) u16 sv[2][128 * 64];
  const int tid = threadIdx.x, wid = tid >> 6, lane = tid & 63;
  const int g = lane >> 4;
  const int qt = blockIdx.x, split = blockIdx.y, b = blockIdx.z;
  const size_t qg0 = (size_t)b * 2048 + qt * 64 + wid * 16;
  const u16* kbase = kb + ((size_t)b * 2048 + split * 512) * 128;
  const u16* vbase = vt + (size_t)b * 262144 + split * 512;

  auto STAGE = [&](int buf, int t) {
#pragma unroll
    for (int i = 0; i < 4; ++i) {  // K-tile: 64 rows x 16 chunks of 16B
      int fc = i * 256 + tid; int r = fc >> 4, c = fc & 15;
      gl_lds16(kbase + (size_t)(t * 64 + r) * 128 + ((c ^ (r & 7)) << 3),
               (char*)&sk[buf][0] + fc * 16);
    }
#pragma unroll
    for (int i = 0; i < 4; ++i) {  // V^T-tile: 128 rows x 8 chunks of 16B
      int fc = i * 256 + tid; int r = fc >> 3, c = fc & 7;
      gl_lds16(vbase + (size_t)r * 2048 + t * 64 + ((c ^ (r & 7)) << 3),
               (char*)&sv[buf][0] + fc * 16);
    }
  };

  STAGE(0, 0);
  // Q fragment (B-operand): col q = lane&15, k-slots g*8+e -> d = kg*32+g*8+e.
  bf16x8 qf[4];
#pragma unroll
  for (int kg = 0; kg < 4; ++kg)
    qf[kg] = *(const bf16x8*)&qb[(qg0 + (lane & 15)) * 128 + kg * 32 + g * 8];

  float m_run = -INFINITY, l_run = 0.f;
  f32x4 acc_o[8] = {};
  const float scale = 0.08838834764831845f;   // 128^-0.5

  asm volatile("s_waitcnt vmcnt(0)" ::: "memory");
  __syncthreads();
  int cur = 0;

  for (int t = 0; t < 8; ++t) {
    if (t < 7) STAGE(cur ^ 1, t + 1);
    const u16* skc = &sk[cur][0];
    const u16* svc = &sv[cur][0];

    // S^T[j][q]: lane holds q = lane&15, j = jg*16 + g*4 + r.
    f32x4 sT[4] = {};
#pragma unroll
    for (int kg = 0; kg < 4; ++kg)
#pragma unroll
      for (int jg = 0; jg < 4; ++jg) {
        int row = jg * 16 + (lane & 15);
        int ch = (kg * 4 + g) ^ (row & 7);
        bf16x8 kf = *(const bf16x8*)(skc + row * 128 + ch * 8);
        sT[jg] = __builtin_amdgcn_mfma_f32_16x16x32_bf16(kf, qf[kg], sT[jg], 0, 0, 0);
      }

    // lane-local online softmax (max in unscaled domain; scale folded via fma)
    float mx = fmaxf(fmaxf(fmaxf(sT[0][0], sT[0][1]), fmaxf(sT[0][2], sT[0][3])),
                     fmaxf(fmaxf(sT[1][0], sT[1][1]), fmaxf(sT[1][2], sT[1][3])));
    mx = fmaxf(mx, fmaxf(fmaxf(fmaxf(sT[2][0], sT[2][1]), fmaxf(sT[2][2], sT[2][3])),
                         fmaxf(fmaxf(sT[3][0], sT[3][1]), fmaxf(sT[3][2], sT[3][3]))));
    mx = fmaxf(mx, __shfl_xor(mx, 16));
    mx = fmaxf(mx, __shfl_xor(mx, 32));
    float mn = fmaxf(m_run, mx * scale);

    float rs = 0.f;
    u32 Wp[4][2];
#pragma unroll
    for (int jg = 0; jg < 4; ++jg) {
      float e0 = __expf(fmaf(sT[jg][0], scale, -mn));
      float e1 = __expf(fmaf(sT[jg][1], scale, -mn));
      float e2 = __expf(fmaf(sT[jg][2], scale, -mn));
      float e3 = __expf(fmaf(sT[jg][3], scale, -mn));
      rs += (e0 + e1) + (e2 + e3);
      Wp[jg][0] = pk2(e0, e1);
      Wp[jg][1] = pk2(e2, e3);
    }
    rs += __shfl_xor(rs, 16);
    rs += __shfl_xor(rs, 32);
    float a = __expf(m_run - mn);
    l_run = l_run * a + rs;
    m_run = mn;
#pragma unroll
    for (int dg = 0; dg < 8; ++dg) acc_o[dg] *= a;

    // P B-fragment: lane's own words, in sigma order (no shuffles).
    bf16x8 pfr[2];
#pragma unroll
    for (int k2 = 0; k2 < 2; ++k2) {
      u32x4 wv = {Wp[2 * k2][0], Wp[2 * k2][1], Wp[2 * k2 + 1][0], Wp[2 * k2 + 1][1]};
      pfr[k2] = __builtin_bit_cast(bf16x8, wv);
    }

    // O += mfma(A=V^T sigma-ordered, B=P).  A k-slot g*8+e needs
    // V^T[row][32k2 + 16*(e>>2) + 4g + (e&3)] -> two b64 reads.
    const int vb = 4 * (g & 1);
#pragma unroll
    for (int dg = 0; dg < 8; ++dg) {
      int row = dg * 16 + (lane & 15);
#pragma unroll
      for (int k2 = 0; k2 < 2; ++k2) {
        int c0 = (4 * k2 + (g >> 1)) ^ (row & 7);
        int c1 = (4 * k2 + 2 + (g >> 1)) ^ (row & 7);
        u32x2 lo = *(const u32x2*)(svc + row * 64 + c0 * 8 + vb);
        u32x2 hi = *(const u32x2*)(svc + row * 64 + c1 * 8 + vb);
        u32x4 w4 = {lo[0], lo[1], hi[0], hi[1]};
        bf16x8 vf = __builtin_bit_cast(bf16x8, w4);
        acc_o[dg] = __builtin_amdgcn_mfma_f32_16x16x32_bf16(vf, pfr[k2], acc_o[dg], 0, 0, 0);
      }
    }
    if (t < 7) {
      asm volatile("s_waitcnt vmcnt(0)" ::: "memory");
      __syncthreads();
      cur ^= 1;
    }
  }

  // store: lane owns q = qg0+(lane&15); acc_o[dg][r] = O[q][dg*16+g*4+r]
  const size_t prow = (size_t)split * 8192 + qg0;
#pragma unroll
  for (int dg = 0; dg < 8; ++dg)
    *(f32x4*)&Opart[(prow + (lane & 15)) * 128 + dg * 16 + g * 4] = acc_o[dg];
  if (lane < 16) {
    Mws[prow + lane] = m_run;
    Lws[prow + lane] = l_run;
  }
}

// ---------------- combine the 4 KV-split partials (f32x4 vectorized) --------
__global__ __launch_bounds__(256) void combine_kernel(
    const float* __restrict__ Opart, const float* __restrict__ Mws,
    const float* __restrict__ Lws, float* __restrict__ out)
{
  int idx4 = blockIdx.x * 256 + threadIdx.x;   // 0..262143 (f32x4 units)
  int row = idx4 >> 5;
  float m0 = Mws[row], m1 = Mws[8192 + row], m2 = Mws[16384 + row], m3 = Mws[24576 + row];
  float ms = fmaxf(fmaxf(m0, m1), fmaxf(m2, m3));
  float w0 = __expf(m0 - ms), w1 = __expf(m1 - ms), w2 = __expf(m2 - ms), w3 = __expf(m3 - ms);
  float den = w0 * Lws[row] + w1 * Lws[8192 + row] + w2 * Lws[16384 + row] + w3 * Lws[24576 + row];
  float inv = 1.0f / den;
  f32x4 o0 = *(const f32x4*)&Opart[(size_t)idx4 * 4];
  f32x4 o1 = *(const f32x4*)&Opart[1048576 + (size_t)idx4 * 4];
  f32x4 o2 = *(const f32x4*)&Opart[2097152 + (size_t)idx4 * 4];
  f32x4 o3 = *(const f32x4*)&Opart[3145728 + (size_t)idx4 * 4];
  f32x4 r = (o0 * w0 + o1 * w1 + o2 * w2 + o3 * w3) * inv;
  *(f32x4*)&out[(size_t)idx4 * 4] = r;
}

// ---------------- launch ----------------------------------------------------
extern "C" void kernel_launch(void* const* d_in, const int* in_sizes, int n_in,
                              void* d_out, int out_size, void* d_ws, size_t ws_size,
                              hipStream_t stream)
{
  (void)in_sizes; (void)n_in; (void)out_size; (void)ws_size;
  const float* x  = (const float*)d_in[0];
  const float* Wq = (const float*)d_in[1];
  const float* bq = (const float*)d_in[2];
  const float* Wk = (const float*)d_in[3];
  const float* bk = (const float*)d_in[4];
  const float* Wv = (const float*)d_in[5];
  const float* bv = (const float*)d_in[6];
  char* ws = (char*)d_ws;
  u16* qbuf   = (u16*)(ws);
  u16* kbuf   = (u16*)(ws + (2u << 20));
  u16* vtbuf  = (u16*)(ws + (4u << 20));
  u16* Wt     = (u16*)(ws + (6u << 20));
  float* Opart = (float*)(ws + (7u << 20));
  float* Mws   = (float*)(ws + (23u << 20));
  float* Lws   = (float*)(ws + (23u << 20) + (128u << 10));

  wprep_kernel<<<96, 256, 0, stream>>>(Wq, Wk, Wv, Wt);
  qkv_gemm<<<dim3(128, 3), 256, 0, stream>>>(x, Wt, bq, bk, bv, qbuf, kbuf, vtbuf);
  attn_kernel<<<dim3(32, 4, 4), 256, 0, stream>>>(qbuf, kbuf, vtbuf, Opart, Mws, Lws);
  combine_kernel<<<1024, 256, 0, stream>>>(Opart, Mws, Lws, (float*)d_out);
}